// Round 15
// baseline (202.611 us; speedup 1.0000x reference)
//
#include <hip/hip_runtime.h>

// Fused cross-attention: out = concat(dec, softmax_e(enc·dec^T)^T-weighted enc)
// B=8, T_enc=T_dec=2048, D=512, fp32 in/out.
// R15 (= R14 + intrinsic-name fix): two independent barrier groups per CU —
//      256-thread blocks (4 waves), TBLK=32, EBLK=16, LDS 50KB -> 2 blocks/CU
//      at full 256-reg budget. Block A's barrier drains overlap block B's
//      compute (m114 mechanism). PV uses mfma_f32_16x16x16f16 (K=16 chunk).
//      Otherwise R13 logic: S4 merge, softmax fast path, T13 defer-max,
//      deferred KT-write.

typedef _Float16 f16;
typedef f16 f16x8 __attribute__((ext_vector_type(8)));
typedef f16 f16x4 __attribute__((ext_vector_type(4)));
typedef f16 f16x2 __attribute__((ext_vector_type(2)));
typedef float f32x4 __attribute__((ext_vector_type(4)));
typedef float f32x2 __attribute__((ext_vector_type(2)));

#define NB 8
#define TE 2048
#define TD 2048
#define DD 512
#define TBLK 32
#define EBLK 16
#define NCH (TE / EBLK)

// LDS layout (bytes) — audited: end 50080; 2 blocks/CU (100160 <= 163840)
#define OKHI 0          // [16 e][512 d] f16 = 16384B, 1024B swizzled rows (QK A)
#define OKT  16384      // [512 d][20 e] f16 = 20480B, 40B rows, sig=(d>>2&1)<<4 (PV A)
#define OS4  36864      // 4 kq x [32 t][20 e] f32 = 10240B (80B rows)
#define OP   47104      // 2 x [32 t][20 e] f16 = 2560B, 40B rows
#define OPSZ 1280
#define OAL  49664      // 2 x 32 f32 alpha
#define OLL  49920      // 32 f32 l
#define OFLG 50048      // 2 x 4 u32 rescale flags
#define SMEM_BYTES 50080

__device__ __forceinline__ int swz1k(int row, int byteInRow) {
    return row * 1024 + (byteInRow ^ ((row & 7) << 4));
}

__global__ __launch_bounds__(256, 2)
void attn_fused(const float* __restrict__ enc, const float* __restrict__ dec,
                float* __restrict__ out) {
    __shared__ __align__(16) char sm[SMEM_BYTES];
    const int tid  = threadIdx.x;
    const int b    = blockIdx.x & 7;          // XCD-pinned batch (enc[b]=4MB fits XCD L2)
    const int t0   = (blockIdx.x >> 3) * TBLK;
    const int lane = tid & 63;
    const int wv   = tid >> 6;                // 0..3 = kq: d in [128wv, 128wv+128)
    const int li   = lane & 15;
    const int gi   = lane >> 4;
    const float L2E = 1.44269504088896f;

    const float* encB = enc + (size_t)b * TE * DD;
    const float* decB = dec + (size_t)b * TD * DD;
    float*       outB = out + (size_t)b * TD * (2 * DD);

    // staging map: c4 = d-quad 0..127, rb = tid>>7 in {0,1} (e rows 8rb..8rb+7)
    const int c4 = tid & 127;
    const int rb = tid >> 7;

    // ---- issue K0 loads ----
    f32x4 st[8];
    #pragma unroll
    for (int i = 0; i < 8; ++i)
        st[i] = *(const f32x4*)(encB + (size_t)(8 * rb + i) * DD + 4 * c4);

    // ---- Q fragments (f16): wave kq covers t = t0+16tl+li, d-slice 128wv ----
    f16x8 qF[4][2];
    #pragma unroll
    for (int kk = 0; kk < 4; ++kk)
        #pragma unroll
        for (int tl = 0; tl < 2; ++tl) {
            const float* qp = decB + (size_t)(t0 + 16 * tl + li) * DD
                            + 128 * wv + 32 * kk + 8 * gi;
            f32x4 q0 = *(const f32x4*)qp;
            f32x4 q1 = *(const f32x4*)(qp + 4);
            f16x8 h;
            #pragma unroll
            for (int j = 0; j < 4; ++j) { h[j] = (f16)q0[j]; h[4 + j] = (f16)q1[j]; }
            qF[kk][tl] = h;
        }

    // ---- cvt K0 -> hvB + Khi-write(0); KT(0) written in iter 0 phase C ----
    f16x4 hvB[8];
    #pragma unroll
    for (int i = 0; i < 8; ++i) {
        f16x4 h4 = {(f16)st[i][0], (f16)st[i][1], (f16)st[i][2], (f16)st[i][3]};
        hvB[i] = h4;
        *(f16x4*)(sm + OKHI + swz1k(8 * rb + i, 8 * c4)) = h4;
    }
    // issue K1 loads
    #pragma unroll
    for (int i = 0; i < 8; ++i)
        st[i] = *(const f32x4*)(encB + (size_t)(EBLK + 8 * rb + i) * DD + 4 * c4);
    __syncthreads();

    // softmax ownership: wave owns t-cols [8wv, 8wv+8); 8 lanes/col, 2 e/lane
    const int cq   = lane & 7;
    const int erq  = lane >> 3;               // 0..7 -> e rows 2erq, 2erq+1
    const int tcol = 8 * wv + cq;
    float mrun = -1.0e30f;
    float lpart = 0.0f;

    f32x4 ctx[8][2];                          // d [128wv,128wv+128) x t [0,32)
    #pragma unroll
    for (int md = 0; md < 8; ++md) {
        ctx[md][0] = (f32x4){0.f, 0.f, 0.f, 0.f};
        ctx[md][1] = (f32x4){0.f, 0.f, 0.f, 0.f};
    }

    for (int ch = 0; ch < NCH; ++ch) {
        const int pb = ch & 1;
        const int qb = pb ^ 1;
        const bool doPV = (ch > 0);
        const bool more = (ch + 1 < NCH);

        // ---- phase A: QK(ch): wave kq -> S[16e x 32t] over its 128d ----
        f32x4 sacc[2];
        sacc[0] = (f32x4){0.f, 0.f, 0.f, 0.f};
        sacc[1] = (f32x4){0.f, 0.f, 0.f, 0.f};
        __builtin_amdgcn_s_setprio(1);
        #pragma unroll
        for (int kk = 0; kk < 4; ++kk) {
            f16x8 aF = *(const f16x8*)(sm + OKHI + swz1k(li, 256 * wv + 64 * kk + 16 * gi));
            sacc[0] = __builtin_amdgcn_mfma_f32_16x16x32_f16(aF, qF[kk][0], sacc[0], 0, 0, 0);
            sacc[1] = __builtin_amdgcn_mfma_f32_16x16x32_f16(aF, qF[kk][1], sacc[1], 0, 0, 0);
        }
        __builtin_amdgcn_s_setprio(0);
        #pragma unroll
        for (int tl = 0; tl < 2; ++tl)
            *(f32x4*)(sm + OS4 + wv * 2560 + (16 * tl + li) * 80 + 16 * gi) = sacc[tl];
        __syncthreads();                                   // B1

        // ---- phase B: softmax(ch) ∥ PV(ch-1) ∥ Khi(ch+1) ∥ loads(ch+2) ----
        f32x2 s2 = (f32x2){0.f, 0.f};
        #pragma unroll
        for (int bu = 0; bu < 4; ++bu)
            s2 += *(const f32x2*)(sm + OS4 + bu * 2560 + tcol * 80 + 8 * erq);

        bool doR = false;
        f16x4 bP[2];
        if (doPV) {
            uint4 fl = *(const uint4*)(sm + OFLG + 16 * qb);
            doR = (fl.x | fl.y | fl.z | fl.w) != 0;
            #pragma unroll
            for (int tt = 0; tt < 2; ++tt)
                bP[tt] = *(const f16x4*)(sm + OP + OPSZ * qb + (16 * tt + li) * 40 + 8 * gi);
        }
        // softmax(ch): fast path has zero cross-lane ops
        {
            float pml = fmaxf(s2[0], s2[1]);
            bool trip = pml > mrun + 8.0f;                 // T13 defer-max
            unsigned long long bal = __ballot(trip);
            float alpha = 1.0f;
            if (bal != 0ULL) {                             // wave-uniform slow path
                float pm = pml;
                pm = fmaxf(pm, __shfl_xor(pm, 8));
                pm = fmaxf(pm, __shfl_xor(pm, 16));
                pm = fmaxf(pm, __shfl_xor(pm, 32));
                float mnew = fmaxf(mrun, pm);
                alpha = exp2f((mrun - mnew) * L2E);
                lpart *= alpha;
                mrun = mnew;
            }
            float p0 = exp2f((s2[0] - mrun) * L2E);
            float p1 = exp2f((s2[1] - mrun) * L2E);
            lpart += p0 + p1;
            f16x2 pw = {(f16)p0, (f16)p1};
            *(f16x2*)(sm + OP + OPSZ * pb + tcol * 40 + 4 * erq) = pw;
            if (erq == 0) *(float*)(sm + OAL + 128 * pb + 4 * tcol) = alpha;
            if (lane == 0) *(unsigned*)(sm + OFLG + 16 * pb + 4 * wv) = (bal != 0ULL) ? 1u : 0u;
        }
        // PV(ch-1): KT holds chunk ch-1 (written in phase C of iter ch-1)
        if (doPV) {
            if (doR) {
                float av[2];
                #pragma unroll
                for (int tt = 0; tt < 2; ++tt)
                    av[tt] = *(const float*)(sm + OAL + 128 * qb + 4 * (16 * tt + li));
                #pragma unroll
                for (int md = 0; md < 8; ++md)
                    #pragma unroll
                    for (int tt = 0; tt < 2; ++tt)
                        #pragma unroll
                        for (int r = 0; r < 4; ++r) ctx[md][tt][r] *= av[tt];
            }
            __builtin_amdgcn_s_setprio(1);
            #pragma unroll
            for (int md = 0; md < 8; ++md) {
                int dv = 128 * wv + 16 * md + li;
                int sig = ((dv >> 2) & 1) << 4;
                f16x4 aV = *(const f16x4*)(sm + OKT + dv * 40 + ((8 * gi) ^ sig));
                ctx[md][0] = __builtin_amdgcn_mfma_f32_16x16x16f16(aV, bP[0], ctx[md][0], 0, 0, 0);
                ctx[md][1] = __builtin_amdgcn_mfma_f32_16x16x16f16(aV, bP[1], ctx[md][1], 0, 0, 0);
            }
            __builtin_amdgcn_s_setprio(0);
        }
        // cvt st(ch+1) -> hvA + Khi-write(ch+1); issue loads(ch+2)
        f16x4 hvA[8];
        if (more) {
            #pragma unroll
            for (int i = 0; i < 8; ++i) {
                f16x4 h4 = {(f16)st[i][0], (f16)st[i][1], (f16)st[i][2], (f16)st[i][3]};
                hvA[i] = h4;
                *(f16x4*)(sm + OKHI + swz1k(8 * rb + i, 8 * c4)) = h4;
            }
            if (ch + 2 < NCH) {
                const float* src = encB + (size_t)(ch + 2) * EBLK * DD;
                #pragma unroll
                for (int i = 0; i < 8; ++i)
                    st[i] = *(const f32x4*)(src + (size_t)(8 * rb + i) * DD + 4 * c4);
            }
        }
        __syncthreads();                                   // B2
        // ---- phase C: KT-write(ch) from hvB ----
        #pragma unroll
        for (int k = 0; k < 4; ++k) {
            int d = 4 * c4 + k;
            int sig = (c4 & 1) << 4;                       // = ((d>>2)&1)<<4
            f16x8 q8 = {hvB[0][k], hvB[1][k], hvB[2][k], hvB[3][k],
                        hvB[4][k], hvB[5][k], hvB[6][k], hvB[7][k]};
            *(f16x8*)(sm + OKT + d * 40 + ((16 * rb) ^ sig)) = q8;
        }
        if (more) {
            #pragma unroll
            for (int i = 0; i < 8; ++i) hvB[i] = hvA[i];
        }
    }

    __syncthreads();   // KT(NCH-1) written in last phase C

    // ---- final PV(NCH-1) ----
    {
        const int qb2 = (NCH - 1) & 1;
        uint4 fl = *(const uint4*)(sm + OFLG + 16 * qb2);
        bool doR = (fl.x | fl.y | fl.z | fl.w) != 0;
        f16x4 bP[2];
        #pragma unroll
        for (int tt = 0; tt < 2; ++tt)
            bP[tt] = *(const f16x4*)(sm + OP + OPSZ * qb2 + (16 * tt + li) * 40 + 8 * gi);
        if (doR) {
            float av[2];
            #pragma unroll
            for (int tt = 0; tt < 2; ++tt)
                av[tt] = *(const float*)(sm + OAL + 128 * qb2 + 4 * (16 * tt + li));
            #pragma unroll
            for (int md = 0; md < 8; ++md)
                #pragma unroll
                for (int tt = 0; tt < 2; ++tt)
                    #pragma unroll
                    for (int r = 0; r < 4; ++r) ctx[md][tt][r] *= av[tt];
        }
        #pragma unroll
        for (int md = 0; md < 8; ++md) {
            int dv = 128 * wv + 16 * md + li;
            int sig = ((dv >> 2) & 1) << 4;
            f16x4 aV = *(const f16x4*)(sm + OKT + dv * 40 + ((8 * gi) ^ sig));
            ctx[md][0] = __builtin_amdgcn_mfma_f32_16x16x16f16(aV, bP[0], ctx[md][0], 0, 0, 0);
            ctx[md][1] = __builtin_amdgcn_mfma_f32_16x16x16f16(aV, bP[1], ctx[md][1], 0, 0, 0);
        }
    }

    // ---- epilogue: reduce per-lane l partials once, normalize, write ----
    {
        float ps = lpart;
        ps += __shfl_xor(ps, 8);
        ps += __shfl_xor(ps, 16);
        ps += __shfl_xor(ps, 32);
        if (erq == 0) *(float*)(sm + OLL + 4 * tcol) = ps;
    }
    __syncthreads();
    float inv[2];
    #pragma unroll
    for (int tt = 0; tt < 2; ++tt)
        inv[tt] = 1.0f / *(const float*)(sm + OLL + 4 * (16 * tt + li));
    #pragma unroll
    for (int md = 0; md < 8; ++md)
        #pragma unroll
        for (int tt = 0; tt < 2; ++tt) {
            int t = t0 + 16 * tt + li;
            int d = 128 * wv + 16 * md + 4 * gi;
            float4 o;
            o.x = ctx[md][tt][0] * inv[tt];
            o.y = ctx[md][tt][1] * inv[tt];
            o.z = ctx[md][tt][2] * inv[tt];
            o.w = ctx[md][tt][3] * inv[tt];
            *(float4*)(outB + (size_t)t * (2 * DD) + DD + d) = o;
        }
    #pragma unroll
    for (int it = 0; it < TBLK * (DD / 4) / 256; ++it) {
        int i = tid + it * 256;
        int t = i >> 7, cc = i & 127;
        float4 q = ((const float4*)(decB + (size_t)(t0 + t) * DD))[cc];
        ((float4*)(outB + (size_t)(t0 + t) * (2 * DD)))[cc] = q;
    }
}

extern "C" void kernel_launch(void* const* d_in, const int* in_sizes, int n_in,
                              void* d_out, int out_size, void* d_ws, size_t ws_size,
                              hipStream_t stream) {
    const float* enc = (const float*)d_in[0];
    const float* dec = (const float*)d_in[1];
    float* out = (float*)d_out;
    dim3 grid(NB * (TD / TBLK));   // 512 blocks = 2/CU; b = bid&7 (XCD pin)
    dim3 block(256);
    attn_fused<<<grid, block, 0, stream>>>(enc, dec, out);
}

// Round 16
// 133.013 us; speedup vs baseline: 1.5232x; 1.5232x over previous
//
#include <hip/hip_runtime.h>

// Fused cross-attention: out = concat(dec, softmax_e(enc·dec^T)^T-weighted enc)
// B=8, T_enc=T_dec=2048, D=512, fp32 in/out.
// R16: R13 + S-partial buffer in f16 (halves the S4 LDS round-trip, the
//      largest remaining LDS item; LDS 121.7K -> 103K). Accuracy cost ~+0.01
//      absmax (partials |max|~50, f16 rel 2^-11). Everything else identical
//      to R13: (et,kq) QK map (no aF dup), softmax fast path, T13 defer-max,
//      deferred KT-write, 2-barrier pipeline, XCD-pinned batch.

typedef _Float16 f16;
typedef f16 f16x8 __attribute__((ext_vector_type(8)));
typedef f16 f16x4 __attribute__((ext_vector_type(4)));
typedef float f32x4 __attribute__((ext_vector_type(4)));

#define NB 8
#define TE 2048
#define TD 2048
#define DD 512
#define TBLK 64
#define EBLK 32
#define NCH (TE / EBLK)

// LDS layout (bytes) — audited: end 103232 < 163840
#define OKHI 0          // [32 e][512 d] f16 = 32768B, 1024B swizzled rows (QK A)
#define OKT  32768      // [512 d][40 e] f16 = 40960B, 80B rows, sig-swizzled (PV A)
#define OS4  73728      // 4 kq x [64 t][36 e] f16 = 18432B (72B rows)
#define OP   92160      // 2 x [64 t][40 e] f16 = 10240B, 80B rows
#define OPSZ 5120
#define OAL  102400     // 2 x 64 f32 alpha
#define OLL  102912     // 64 f32 l
#define OFLG 103168     // 2 x 8 u32 rescale flags
#define SMEM_BYTES 103232

__device__ __forceinline__ int swz1k(int row, int byteInRow) {
    return row * 1024 + (byteInRow ^ ((row & 7) << 4));
}

__global__ __launch_bounds__(512, 2)
void attn_fused(const float* __restrict__ enc, const float* __restrict__ dec,
                float* __restrict__ out) {
    __shared__ __align__(16) char sm[SMEM_BYTES];
    const int tid  = threadIdx.x;
    const int b    = blockIdx.x & 7;          // XCD-pinned batch
    const int t0   = (blockIdx.x >> 3) * TBLK;
    const int lane = tid & 63;
    const int wv   = tid >> 6;
    const int li   = lane & 15;
    const int gi   = lane >> 4;
    const int et   = wv & 1;                  // e-tile: e in [16et, 16et+16)
    const int kq   = wv >> 1;                 // k-slice: d in [128kq, 128kq+128)
    const float L2E = 1.44269504088896f;

    const float* encB = enc + (size_t)b * TE * DD;
    const float* decB = dec + (size_t)b * TD * DD;
    float*       outB = out + (size_t)b * TD * (2 * DD);

    // staging map: c4 = d-quad 0..127, rb = e-octet 0..3 (e rows 8rb..8rb+7)
    const int c4 = tid & 127;
    const int rb = tid >> 7;

    // ---- issue K0 loads ----
    f32x4 st[8];
    #pragma unroll
    for (int i = 0; i < 8; ++i)
        st[i] = *(const f32x4*)(encB + (size_t)(8 * rb + i) * DD + 4 * c4);

    // ---- Q fragments (f16) direct from global: all 64 t, k-slice kq ----
    f16x8 qF[4][4];
    #pragma unroll
    for (int kk = 0; kk < 4; ++kk)
        #pragma unroll
        for (int tl = 0; tl < 4; ++tl) {
            const float* qp = decB + (size_t)(t0 + 16 * tl + li) * DD
                            + 128 * kq + 32 * kk + 8 * gi;
            f32x4 q0 = *(const f32x4*)qp;
            f32x4 q1 = *(const f32x4*)(qp + 4);
            f16x8 h;
            #pragma unroll
            for (int j = 0; j < 4; ++j) { h[j] = (f16)q0[j]; h[4 + j] = (f16)q1[j]; }
            qF[kk][tl] = h;
        }

    // ---- cvt K0 -> hvB + Khi-write(0); KT(0) written in iter 0 phase C ----
    f16x4 hvB[8];
    #pragma unroll
    for (int i = 0; i < 8; ++i) {
        f16x4 h4 = {(f16)st[i][0], (f16)st[i][1], (f16)st[i][2], (f16)st[i][3]};
        hvB[i] = h4;
        *(f16x4*)(sm + OKHI + swz1k(8 * rb + i, 8 * c4)) = h4;
    }
    // issue K1 loads
    #pragma unroll
    for (int i = 0; i < 8; ++i)
        st[i] = *(const f32x4*)(encB + (size_t)(EBLK + 8 * rb + i) * DD + 4 * c4);
    __syncthreads();

    // softmax ownership: wave owns t-cols [8wv, 8wv+8); 8 lanes/col, 4 e/lane
    const int cq   = lane & 7;
    const int erq  = lane >> 3;               // 0..7 -> e rows 4erq..4erq+3
    const int tcol = 8 * wv + cq;
    float mrun = -1.0e30f;
    float lpart = 0.0f;                       // per-lane partial of l (4 e-slots)

    f32x4 ctx[4][4];                          // d [64wv,64wv+64) x t [0,64)
    #pragma unroll
    for (int md = 0; md < 4; ++md)
        #pragma unroll
        for (int tt = 0; tt < 4; ++tt)
            ctx[md][tt] = (f32x4){0.f, 0.f, 0.f, 0.f};

    for (int ch = 0; ch < NCH; ++ch) {
        const int pb = ch & 1;
        const int qb = pb ^ 1;
        const bool doPV = (ch > 0);
        const bool more = (ch + 1 < NCH);

        // ---- phase A: QK(ch), S4 partial writes (f16) ----
        // wave (et,kq): S[16et..16et+16) x [0,64) for d in [128kq,128kq+128)
        f32x4 sacc[4];
        #pragma unroll
        for (int tl = 0; tl < 4; ++tl)
            sacc[tl] = (f32x4){0.f, 0.f, 0.f, 0.f};
        __builtin_amdgcn_s_setprio(1);
        #pragma unroll
        for (int kk = 0; kk < 4; ++kk) {
            int cb = 256 * kq + 64 * kk + 16 * gi;
            f16x8 aF = *(const f16x8*)(sm + OKHI + swz1k(16 * et + li, cb));
            #pragma unroll
            for (int tl = 0; tl < 4; ++tl)
                sacc[tl] = __builtin_amdgcn_mfma_f32_16x16x32_f16(aF, qF[kk][tl], sacc[tl], 0, 0, 0);
        }
        __builtin_amdgcn_s_setprio(0);
        #pragma unroll
        for (int tl = 0; tl < 4; ++tl) {
            f16x4 sh = {(f16)sacc[tl][0], (f16)sacc[tl][1],
                        (f16)sacc[tl][2], (f16)sacc[tl][3]};
            *(f16x4*)(sm + OS4 + kq * 4608 + (16 * tl + li) * 72
                      + 32 * et + 8 * gi) = sh;
        }
        __syncthreads();                                   // B1

        // ---- phase B: softmax(ch) ∥ PV(ch-1) ∥ Khi(ch+1) ∥ loads(ch+2) ----
        f32x4 s4 = (f32x4){0.f, 0.f, 0.f, 0.f};
        #pragma unroll
        for (int bu = 0; bu < 4; ++bu) {
            f16x4 h = *(const f16x4*)(sm + OS4 + bu * 4608 + tcol * 72 + 8 * erq);
            #pragma unroll
            for (int j = 0; j < 4; ++j) s4[j] += (float)h[j];
        }

        bool doR = false;
        f16x8 bP[4];
        if (doPV) {
            const uint4* fp = (const uint4*)(sm + OFLG + 32 * qb);
            uint4 f0 = fp[0], f1 = fp[1];
            doR = (f0.x | f0.y | f0.z | f0.w | f1.x | f1.y | f1.z | f1.w) != 0;
            #pragma unroll
            for (int tt = 0; tt < 4; ++tt)
                bP[tt] = *(const f16x8*)(sm + OP + OPSZ * qb + (16 * tt + li) * 80 + 16 * gi);
        }
        // softmax(ch): fast path has zero cross-lane ops
        {
            float pml = fmaxf(fmaxf(s4[0], s4[1]), fmaxf(s4[2], s4[3]));
            bool trip = pml > mrun + 8.0f;                 // T13 defer-max
            unsigned long long bal = __ballot(trip);
            float alpha = 1.0f;
            if (bal != 0ULL) {                             // wave-uniform slow path
                float pm = pml;
                pm = fmaxf(pm, __shfl_xor(pm, 8));
                pm = fmaxf(pm, __shfl_xor(pm, 16));
                pm = fmaxf(pm, __shfl_xor(pm, 32));
                float mnew = fmaxf(mrun, pm);
                alpha = exp2f((mrun - mnew) * L2E);
                lpart *= alpha;
                mrun = mnew;
            }
            f32x4 p4;
            #pragma unroll
            for (int j = 0; j < 4; ++j) p4[j] = exp2f((s4[j] - mrun) * L2E);
            lpart += p4[0] + p4[1] + p4[2] + p4[3];
            f16x4 pw = {(f16)p4[0], (f16)p4[1], (f16)p4[2], (f16)p4[3]};
            *(f16x4*)(sm + OP + OPSZ * pb + tcol * 80 + 8 * erq) = pw;
            if (erq == 0) *(float*)(sm + OAL + 256 * pb + 4 * tcol) = alpha;
            if (lane == 0) *(unsigned*)(sm + OFLG + 32 * pb + 4 * wv) = (bal != 0ULL) ? 1u : 0u;
        }
        // PV(ch-1): KT holds chunk ch-1 (written in phase C of iter ch-1)
        if (doPV) {
            if (doR) {
                float av[4];
                #pragma unroll
                for (int tt = 0; tt < 4; ++tt)
                    av[tt] = *(const float*)(sm + OAL + 256 * qb + 4 * (16 * tt + li));
                #pragma unroll
                for (int md = 0; md < 4; ++md)
                    #pragma unroll
                    for (int tt = 0; tt < 4; ++tt)
                        #pragma unroll
                        for (int r = 0; r < 4; ++r) ctx[md][tt][r] *= av[tt];
            }
            __builtin_amdgcn_s_setprio(1);
            #pragma unroll
            for (int md = 0; md < 4; ++md) {
                int dv = 64 * wv + 16 * md + li;
                int sig = ((dv >> 3) & 3) << 4;
                f16x8 a = *(const f16x8*)(sm + OKT + dv * 80 + ((16 * gi) ^ sig));
                #pragma unroll
                for (int tt = 0; tt < 4; ++tt)
                    ctx[md][tt] = __builtin_amdgcn_mfma_f32_16x16x32_f16(a, bP[tt], ctx[md][tt], 0, 0, 0);
            }
            __builtin_amdgcn_s_setprio(0);
        }
        // cvt st(ch+1) -> hvA + Khi-write(ch+1); issue loads(ch+2)
        f16x4 hvA[8];
        if (more) {
            #pragma unroll
            for (int i = 0; i < 8; ++i) {
                f16x4 h4 = {(f16)st[i][0], (f16)st[i][1], (f16)st[i][2], (f16)st[i][3]};
                hvA[i] = h4;
                *(f16x4*)(sm + OKHI + swz1k(8 * rb + i, 8 * c4)) = h4;
            }
            if (ch + 2 < NCH) {
                const float* src = encB + (size_t)(ch + 2) * EBLK * DD;
                #pragma unroll
                for (int i = 0; i < 8; ++i)
                    st[i] = *(const f32x4*)(src + (size_t)(8 * rb + i) * DD + 4 * c4);
            }
        }
        __syncthreads();                                   // B2
        // ---- phase C: KT-write(ch) from hvB ----
        #pragma unroll
        for (int k = 0; k < 4; ++k) {
            int d = 4 * c4 + k;
            int sig = ((d >> 3) & 3) << 4;
            f16x8 q8 = {hvB[0][k], hvB[1][k], hvB[2][k], hvB[3][k],
                        hvB[4][k], hvB[5][k], hvB[6][k], hvB[7][k]};
            *(f16x8*)(sm + OKT + d * 80 + ((16 * rb) ^ sig)) = q8;
        }
        if (more) {
            #pragma unroll
            for (int i = 0; i < 8; ++i) hvB[i] = hvA[i];
        }
    }

    __syncthreads();   // KT(NCH-1) written in last phase C

    // ---- final PV(NCH-1) ----
    {
        const int qb2 = (NCH - 1) & 1;
        const uint4* fp = (const uint4*)(sm + OFLG + 32 * qb2);
        uint4 f0 = fp[0], f1 = fp[1];
        bool doR = (f0.x | f0.y | f0.z | f0.w | f1.x | f1.y | f1.z | f1.w) != 0;
        f16x8 bP[4];
        #pragma unroll
        for (int tt = 0; tt < 4; ++tt)
            bP[tt] = *(const f16x8*)(sm + OP + OPSZ * qb2 + (16 * tt + li) * 80 + 16 * gi);
        if (doR) {
            float av[4];
            #pragma unroll
            for (int tt = 0; tt < 4; ++tt)
                av[tt] = *(const float*)(sm + OAL + 256 * qb2 + 4 * (16 * tt + li));
            #pragma unroll
            for (int md = 0; md < 4; ++md)
                #pragma unroll
                for (int tt = 0; tt < 4; ++tt)
                    #pragma unroll
                    for (int r = 0; r < 4; ++r) ctx[md][tt][r] *= av[tt];
        }
        #pragma unroll
        for (int md = 0; md < 4; ++md) {
            int dv = 64 * wv + 16 * md + li;
            int sig = ((dv >> 3) & 3) << 4;
            f16x8 a = *(const f16x8*)(sm + OKT + dv * 80 + ((16 * gi) ^ sig));
            #pragma unroll
            for (int tt = 0; tt < 4; ++tt)
                ctx[md][tt] = __builtin_amdgcn_mfma_f32_16x16x32_f16(a, bP[tt], ctx[md][tt], 0, 0, 0);
        }
    }

    // ---- epilogue: reduce per-lane l partials once, normalize, write ----
    {
        float ps = lpart;
        ps += __shfl_xor(ps, 8);
        ps += __shfl_xor(ps, 16);
        ps += __shfl_xor(ps, 32);
        if (erq == 0) *(float*)(sm + OLL + 4 * tcol) = ps;
    }
    __syncthreads();
    float inv[4];
    #pragma unroll
    for (int tt = 0; tt < 4; ++tt)
        inv[tt] = 1.0f / *(const float*)(sm + OLL + 4 * (16 * tt + li));
    #pragma unroll
    for (int md = 0; md < 4; ++md)
        #pragma unroll
        for (int tt = 0; tt < 4; ++tt) {
            int t = t0 + 16 * tt + li;
            int d = 64 * wv + 16 * md + 4 * gi;
            float4 o;
            o.x = ctx[md][tt][0] * inv[tt];
            o.y = ctx[md][tt][1] * inv[tt];
            o.z = ctx[md][tt][2] * inv[tt];
            o.w = ctx[md][tt][3] * inv[tt];
            *(float4*)(outB + (size_t)t * (2 * DD) + DD + d) = o;
        }
    #pragma unroll
    for (int it = 0; it < TBLK * (DD / 4) / 512; ++it) {
        int i = tid + it * 512;
        int t = i >> 7, cc = i & 127;
        float4 q = ((const float4*)(decB + (size_t)(t0 + t) * DD))[cc];
        ((float4*)(outB + (size_t)(t0 + t) * (2 * DD)))[cc] = q;
    }
}

extern "C" void kernel_launch(void* const* d_in, const int* in_sizes, int n_in,
                              void* d_out, int out_size, void* d_ws, size_t ws_size,
                              hipStream_t stream) {
    const float* enc = (const float*)d_in[0];
    const float* dec = (const float*)d_in[1];
    float* out = (float*)d_out;
    dim3 grid(NB * (TD / TBLK));   // 256 blocks: b = bid&7 (XCD pin), ttile = bid>>3
    dim3 block(512);
    attn_fused<<<grid, block, 0, stream>>>(enc, dec, out);
}